// Round 6
// baseline (1293.994 us; speedup 1.0000x reference)
//
#include <hip/hip_runtime.h>
#include <hip/hip_bf16.h>
#include <math.h>

// ---------------------------------------------------------------------------
// GIN + JumpingKnowledge(cat) + mean-pool + 2-layer head, eval mode.
// R6: CSC build replaced by two-phase binned scatter:
//   Phase A: edges partitioned into dst-range buckets (dst>>14) via LDS
//            binning, written coalesced to an arena; per-bucket arena bases
//            = rp[bucket_lo] so arena ranges align with col ranges.
//   Phase B: per-bucket scatter (7 launches); col writes land in a ~1MB
//            L2-resident window -> writebacks combine (105MB -> ~10MB).
// agg/mlp/pool/final unchanged from R5 (best so far, 1290us).
// ---------------------------------------------------------------------------

typedef unsigned int uint;
typedef unsigned short ushort;

#define ABITS 14  // bucket = dst >> 14 (16384 nodes/bucket, ~1MB col window)

__device__ __forceinline__ float bf_lo(uint w) { return __uint_as_float(w << 16); }
__device__ __forceinline__ float bf_hi(uint w) { return __uint_as_float(w & 0xffff0000u); }

__device__ __forceinline__ uint pack_bf16(float a, float b) {
  __hip_bfloat16 ha = __float2bfloat16(a);
  __hip_bfloat16 hb = __float2bfloat16(b);
  ushort ua = *(ushort*)&ha, ub = *(ushort*)&hb;
  return (uint)ua | ((uint)ub << 16);
}

__global__ void count_deg_kernel(const int* __restrict__ dst, int* __restrict__ deg, int E) {
  int t = blockIdx.x * blockDim.x + threadIdx.x;
  if (t < E) atomicAdd(&deg[dst[t]], 1);
}

// ---- multi-block exclusive scan: deg[N] -> rp[N+1] (+ cursor copy) --------
__global__ void scan_blocksums(const int* __restrict__ deg, int* __restrict__ bsum, int N) {
  __shared__ int red[256];
  int i = blockIdx.x * 256 + threadIdx.x;
  red[threadIdx.x] = (i < N) ? deg[i] : 0;
  __syncthreads();
  for (int off = 128; off > 0; off >>= 1) {
    if (threadIdx.x < off) red[threadIdx.x] += red[threadIdx.x + off];
    __syncthreads();
  }
  if (threadIdx.x == 0) bsum[blockIdx.x] = red[0];
}

__global__ void scan_bsum(const int* __restrict__ bsum, int* __restrict__ boff,
                          int* __restrict__ rp_last, int B) {
  __shared__ int tmp[1024];
  int t = threadIdx.x;
  int v = (t < B) ? bsum[t] : 0;
  tmp[t] = v;
  __syncthreads();
  for (int off = 1; off < 1024; off <<= 1) {
    int u = (t >= off) ? tmp[t - off] : 0;
    __syncthreads();
    tmp[t] += u;
    __syncthreads();
  }
  if (t < B) boff[t] = tmp[t] - v;
  if (t == 1023) *rp_last = tmp[1023];
}

__global__ void scan_final(const int* __restrict__ deg, const int* __restrict__ boff,
                           int* __restrict__ rp, int* __restrict__ cursor, int N) {
  __shared__ int tmp[256];
  int i = blockIdx.x * 256 + threadIdx.x;
  int v = (i < N) ? deg[i] : 0;
  tmp[threadIdx.x] = v;
  __syncthreads();
  for (int off = 1; off < 256; off <<= 1) {
    int u = (threadIdx.x >= off) ? tmp[threadIdx.x - off] : 0;
    __syncthreads();
    tmp[threadIdx.x] += u;
    __syncthreads();
  }
  if (i < N) {
    int ex = boff[blockIdx.x] + tmp[threadIdx.x] - v;
    rp[i] = ex;
    cursor[i] = ex;
  }
}

// bucket arena cursors: bc[b] = rp[b<<ABITS] (arena ranges == col ranges)
__global__ void init_buckets_kernel(const int* __restrict__ rp, int* __restrict__ bc,
                                    int N, int P) {
  int b = threadIdx.x;
  if (b < P) {
    int lo = b << ABITS;
    if (lo > N) lo = N;
    bc[b] = rp[lo];
  }
}

// Phase A: partition edges into dst-range buckets. 1024 thr x 4 edges/block.
__global__ __launch_bounds__(1024) void bin_edges_kernel(
    const int* __restrict__ src, const int* __restrict__ dst, int* __restrict__ bc,
    int* __restrict__ arena_src, int* __restrict__ arena_dst, int E) {
  __shared__ int cnt[32], base[32];
  for (long chunk = (long)blockIdx.x * 4096; chunk < E; chunk += (long)gridDim.x * 4096) {
    if (threadIdx.x < 32) cnt[threadIdx.x] = 0;
    __syncthreads();
    int s[4], d[4], b[4], r[4];
#pragma unroll
    for (int u = 0; u < 4; ++u) {
      long e = chunk + threadIdx.x + u * 1024;
      if (e < E) {
        s[u] = src[e];
        d[u] = dst[e];
        b[u] = d[u] >> ABITS;
        r[u] = atomicAdd(&cnt[b[u]], 1);
      }
    }
    __syncthreads();
    if (threadIdx.x < 32) base[threadIdx.x] = cnt[threadIdx.x] ? atomicAdd(&bc[threadIdx.x], cnt[threadIdx.x]) : 0;
    __syncthreads();
#pragma unroll
    for (int u = 0; u < 4; ++u) {
      long e = chunk + threadIdx.x + u * 1024;
      if (e < E) {
        int pos = base[b[u]] + r[u];
        arena_src[pos] = s[u];
        arena_dst[pos] = d[u];
      }
    }
    __syncthreads();
  }
}

// Phase B: scatter one bucket; col writes confined to a ~1MB L2-resident window.
__global__ void scatter_bucket_kernel(const int* __restrict__ arena_src,
                                      const int* __restrict__ arena_dst,
                                      const int* __restrict__ rp, int* __restrict__ cursor,
                                      int* __restrict__ col, int lo_node, int hi_node) {
  int start = rp[lo_node], end = rp[hi_node];
  for (int i = start + (int)(blockIdx.x * blockDim.x + threadIdx.x); i < end;
       i += (int)(gridDim.x * blockDim.x)) {
    int s = arena_src[i], d = arena_dst[i];
    int pos = atomicAdd(&cursor[d], 1);
    col[pos] = s;
  }
}

// graph start offsets from sorted batch: gs[g] = first node of graph g, gs[G]=N.
__global__ void graph_bounds_kernel(const int* __restrict__ batch, int* __restrict__ gs,
                                    int N, int G) {
  int n = blockIdx.x * 256 + threadIdx.x;
  if (n >= N) return;
  int b = batch[n];
  int bp = (n == 0) ? -1 : batch[n - 1];
  for (int g = bp + 1; g <= b; ++g) gs[g] = n;
  if (n == N - 1)
    for (int g = b + 1; g <= G; ++g) gs[g] = N;
}

// W1_rest [7][64][64] -> W1T [7][64][64] with W1T[l][k][m] = W1_rest[l][m][k]
__global__ void transpose_w1_kernel(const float* __restrict__ w1rest, float* __restrict__ w1t) {
  int l = blockIdx.x;
  for (int idx = threadIdx.x; idx < 4096; idx += blockDim.x) {
    int k = idx >> 6, m = idx & 63;
    w1t[l * 4096 + idx] = w1rest[l * 4096 + m * 64 + k];
  }
}

// z[n][:] = (1+eps_l)*h[n][:] + sum_e h[col[e]][:]   (h bf16, z fp32)
// 8-lane groups; 4 independent 1KB row-gathers in flight (2 nodes x 2 steps).
__global__ __launch_bounds__(256, 6) void agg_kernel(
    const ushort* __restrict__ hb, const int* __restrict__ rp,
    const int* __restrict__ col, const float* __restrict__ eps,
    int layer, float* __restrict__ z, int N) {
  int lane = threadIdx.x & 63;
  int g = lane >> 3;
  int r = lane & 7;
  int wave = blockIdx.x * (blockDim.x >> 6) + (threadIdx.x >> 6);
  int nwaves = gridDim.x * (blockDim.x >> 6);
  float ep = 1.0f + eps[layer];
  for (int n = wave * 2; n < N; n += nwaves * 2) {
    int n0 = __builtin_amdgcn_readfirstlane(n);
    int n1 = n0 + 1;
    int beg0 = rp[n0];
    int end0 = rp[n0 + 1];
    int end1 = (n1 < N) ? rp[n1 + 1] : end0;
    float a0[8] = {0.f, 0.f, 0.f, 0.f, 0.f, 0.f, 0.f, 0.f};
    float a1[8] = {0.f, 0.f, 0.f, 0.f, 0.f, 0.f, 0.f, 0.f};
    float b0[8] = {0.f, 0.f, 0.f, 0.f, 0.f, 0.f, 0.f, 0.f};
    float b1[8] = {0.f, 0.f, 0.f, 0.f, 0.f, 0.f, 0.f, 0.f};
    int e0 = beg0 + g;
    int e1 = end0 + g;
    while (e0 < end0 || e1 < end1) {
      if (e0 < end0) {
        int s = col[e0];
        uint4 w = ((const uint4*)(hb + (long)s * 64))[r];
        a0[0] += bf_lo(w.x); a0[1] += bf_hi(w.x);
        a0[2] += bf_lo(w.y); a0[3] += bf_hi(w.y);
        a0[4] += bf_lo(w.z); a0[5] += bf_hi(w.z);
        a0[6] += bf_lo(w.w); a0[7] += bf_hi(w.w);
      }
      if (e0 + 8 < end0) {
        int s = col[e0 + 8];
        uint4 w = ((const uint4*)(hb + (long)s * 64))[r];
        a1[0] += bf_lo(w.x); a1[1] += bf_hi(w.x);
        a1[2] += bf_lo(w.y); a1[3] += bf_hi(w.y);
        a1[4] += bf_lo(w.z); a1[5] += bf_hi(w.z);
        a1[6] += bf_lo(w.w); a1[7] += bf_hi(w.w);
      }
      if (e1 < end1) {
        int s = col[e1];
        uint4 w = ((const uint4*)(hb + (long)s * 64))[r];
        b0[0] += bf_lo(w.x); b0[1] += bf_hi(w.x);
        b0[2] += bf_lo(w.y); b0[3] += bf_hi(w.y);
        b0[4] += bf_lo(w.z); b0[5] += bf_hi(w.z);
        b0[6] += bf_lo(w.w); b0[7] += bf_hi(w.w);
      }
      if (e1 + 8 < end1) {
        int s = col[e1 + 8];
        uint4 w = ((const uint4*)(hb + (long)s * 64))[r];
        b1[0] += bf_lo(w.x); b1[1] += bf_hi(w.x);
        b1[2] += bf_lo(w.y); b1[3] += bf_hi(w.y);
        b1[4] += bf_lo(w.z); b1[5] += bf_hi(w.z);
        b1[6] += bf_lo(w.w); b1[7] += bf_hi(w.w);
      }
      e0 += 16; e1 += 16;
    }
#pragma unroll
    for (int j = 0; j < 8; ++j) { a0[j] += a1[j]; b0[j] += b1[j]; }
#pragma unroll
    for (int m = 8; m <= 32; m <<= 1) {
#pragma unroll
      for (int j = 0; j < 8; ++j) {
        a0[j] += __shfl_xor(a0[j], m, 64);
        b0[j] += __shfl_xor(b0[j], m, 64);
      }
    }
    if (g == 0) {
      uint4 hv = ((const uint4*)(hb + (long)n0 * 64))[r];
      float4 z0, z1;
      z0.x = fmaf(ep, bf_lo(hv.x), a0[0]); z0.y = fmaf(ep, bf_hi(hv.x), a0[1]);
      z0.z = fmaf(ep, bf_lo(hv.y), a0[2]); z0.w = fmaf(ep, bf_hi(hv.y), a0[3]);
      z1.x = fmaf(ep, bf_lo(hv.z), a0[4]); z1.y = fmaf(ep, bf_hi(hv.z), a0[5]);
      z1.z = fmaf(ep, bf_lo(hv.w), a0[6]); z1.w = fmaf(ep, bf_hi(hv.w), a0[7]);
      float4* zr = (float4*)(z + (long)n0 * 64 + r * 8);
      zr[0] = z0; zr[1] = z1;
    } else if (g == 1 && n1 < N) {
      uint4 hv = ((const uint4*)(hb + (long)n1 * 64))[r];
      float4 z0, z1;
      z0.x = fmaf(ep, bf_lo(hv.x), b0[0]); z0.y = fmaf(ep, bf_hi(hv.x), b0[1]);
      z0.z = fmaf(ep, bf_lo(hv.y), b0[2]); z0.w = fmaf(ep, bf_hi(hv.y), b0[3]);
      z1.x = fmaf(ep, bf_lo(hv.z), b0[4]); z1.y = fmaf(ep, bf_hi(hv.z), b0[5]);
      z1.z = fmaf(ep, bf_lo(hv.w), b0[6]); z1.w = fmaf(ep, bf_hi(hv.w), b0[7]);
      float4* zr = (float4*)(z + (long)n1 * 64 + r * 8);
      zr[0] = z0; zr[1] = z1;
    }
  }
}

// Fused 64->64->64 MLP + relu/bn twice. One node per lane; z fp32 in, h bf16 out.
__global__ __launch_bounds__(64) void mlp_kernel(
    const float* __restrict__ z, ushort* __restrict__ hout,
    const float* __restrict__ W1T, const float* __restrict__ b1,
    const float* __restrict__ g1, const float* __restrict__ be1,
    const float* __restrict__ m1, const float* __restrict__ v1,
    const float* __restrict__ W2, const float* __restrict__ b2,
    const float* __restrict__ g2, const float* __restrict__ be2,
    const float* __restrict__ m2, const float* __restrict__ v2, int N) {
  int n = blockIdx.x * blockDim.x + threadIdx.x;
  if (n >= N) return;
  float zv[64];
  const float4* zp = (const float4*)(z + (long)n * 64);
#pragma unroll
  for (int q = 0; q < 16; ++q) {
    float4 t = zp[q];
    zv[4 * q + 0] = t.x; zv[4 * q + 1] = t.y; zv[4 * q + 2] = t.z; zv[4 * q + 3] = t.w;
  }
  float out2[64];
#pragma unroll
  for (int j = 0; j < 64; ++j) out2[j] = b2[j];
  for (int k = 0; k < 64; ++k) {
    const float* w1c = W1T + k * 64;
    float t0 = b1[k], t1 = 0.f, t2 = 0.f, t3 = 0.f;
#pragma unroll
    for (int m = 0; m < 16; ++m) {
      t0 = fmaf(zv[4 * m + 0], w1c[4 * m + 0], t0);
      t1 = fmaf(zv[4 * m + 1], w1c[4 * m + 1], t1);
      t2 = fmaf(zv[4 * m + 2], w1c[4 * m + 2], t2);
      t3 = fmaf(zv[4 * m + 3], w1c[4 * m + 3], t3);
    }
    float t = (t0 + t1) + (t2 + t3);
    t = fmaxf(t, 0.f);
    float sc = g1[k] * rsqrtf(v1[k] + 1e-5f);
    t = fmaf(t - m1[k], sc, be1[k]);
    const float* w2r = W2 + k * 64;
#pragma unroll
    for (int j = 0; j < 64; ++j) out2[j] = fmaf(t, w2r[j], out2[j]);
  }
  uint4* hp = (uint4*)(hout + (long)n * 64);
#pragma unroll
  for (int q = 0; q < 8; ++q) {
    float u[8];
#pragma unroll
    for (int c = 0; c < 8; ++c) {
      int j = 8 * q + c;
      float t = fmaxf(out2[j], 0.f);
      u[c] = fmaf(t - m2[j], g2[j] * rsqrtf(v2[j] + 1e-5f), be2[j]);
    }
    uint4 w;
    w.x = pack_bf16(u[0], u[1]);
    w.y = pack_bf16(u[2], u[3]);
    w.z = pack_bf16(u[4], u[5]);
    w.w = pack_bf16(u[6], u[7]);
    hp[q] = w;
  }
}

// Layer 0: scalar input (H_in = 1).  Thread-per-node, fully fused, bf16 out.
__global__ __launch_bounds__(64) void layer0_kernel(
    const float* __restrict__ x, const int* __restrict__ rp, const int* __restrict__ col,
    const float* __restrict__ eps,
    const float* __restrict__ W1f, const float* __restrict__ b1,
    const float* __restrict__ g1, const float* __restrict__ be1,
    const float* __restrict__ m1, const float* __restrict__ v1,
    const float* __restrict__ W2, const float* __restrict__ b2,
    const float* __restrict__ g2, const float* __restrict__ be2,
    const float* __restrict__ m2, const float* __restrict__ v2,
    ushort* __restrict__ hout, int N) {
  int n = blockIdx.x * blockDim.x + threadIdx.x;
  if (n >= N) return;
  int beg = rp[n], end = rp[n + 1];
  float agg = 0.f;
  for (int e = beg; e < end; ++e) agg += x[col[e]];
  float z0 = fmaf(1.0f + eps[0], x[n], agg);
  float out2[64];
#pragma unroll
  for (int j = 0; j < 64; ++j) out2[j] = b2[j];
  for (int k = 0; k < 64; ++k) {
    float t = fmaf(z0, W1f[k], b1[k]);
    t = fmaxf(t, 0.f);
    float sc = g1[k] * rsqrtf(v1[k] + 1e-5f);
    t = fmaf(t - m1[k], sc, be1[k]);
    const float* w2r = W2 + k * 64;
#pragma unroll
    for (int j = 0; j < 64; ++j) out2[j] = fmaf(t, w2r[j], out2[j]);
  }
  uint4* hp = (uint4*)(hout + (long)n * 64);
#pragma unroll
  for (int q = 0; q < 8; ++q) {
    float u[8];
#pragma unroll
    for (int c = 0; c < 8; ++c) {
      int j = 8 * q + c;
      float t = fmaxf(out2[j], 0.f);
      u[c] = fmaf(t - m2[j], g2[j] * rsqrtf(v2[j] + 1e-5f), be2[j]);
    }
    uint4 w;
    w.x = pack_bf16(u[0], u[1]);
    w.y = pack_bf16(u[2], u[3]);
    w.z = pack_bf16(u[4], u[5]);
    w.w = pack_bf16(u[6], u[7]);
    hp[q] = w;
  }
}

// block-per-graph mean-sum using precomputed bounds; no atomics.
__global__ void pool_kernel(const ushort* __restrict__ hb, const int* __restrict__ gs,
                            float* __restrict__ pooled, int layer, int G) {
  int g = blockIdx.x;
  int s = gs[g], e = gs[g + 1];
  int w = threadIdx.x >> 6, lane = threadIdx.x & 63;
  float acc = 0.f;
  for (int n = s + w; n < e; n += 4) {
    ushort u = hb[(long)n * 64 + lane];
    acc += __uint_as_float((uint)u << 16);
  }
  __shared__ float red[4][64];
  red[w][lane] = acc;
  __syncthreads();
  if (w == 0)
    pooled[(long)g * 512 + layer * 64 + lane] =
        ((red[0][lane] + red[1][lane]) + (red[2][lane] + red[3][lane]));
}

__global__ __launch_bounds__(64) void final_kernel(
    const float* __restrict__ pooled, const int* __restrict__ gs,
    const float* __restrict__ lin1_w, const float* __restrict__ lin1_b,
    const float* __restrict__ lin2_w, const float* __restrict__ lin2_b,
    float* __restrict__ out, int G) {
  int g = blockIdx.x;
  int j = threadIdx.x;
  float inv = 1.0f / fmaxf((float)(gs[g + 1] - gs[g]), 1.0f);
  __shared__ float p[512];
  for (int t = j; t < 512; t += 64) p[t] = pooled[(long)g * 512 + t] * inv;
  __syncthreads();
  float a0 = lin1_b[j], a1 = 0.f, a2 = 0.f, a3 = 0.f;
  for (int k = 0; k < 512; k += 4) {
    a0 = fmaf(p[k + 0], lin1_w[(k + 0) * 64 + j], a0);
    a1 = fmaf(p[k + 1], lin1_w[(k + 1) * 64 + j], a1);
    a2 = fmaf(p[k + 2], lin1_w[(k + 2) * 64 + j], a2);
    a3 = fmaf(p[k + 3], lin1_w[(k + 3) * 64 + j], a3);
  }
  float hv = fmaxf((a0 + a1) + (a2 + a3), 0.f);
  __shared__ float hb[64];
  hb[j] = hv;
  __syncthreads();
  __shared__ float lg[3];
  if (j < 3) {
    float a = lin2_b[j];
#pragma unroll
    for (int k = 0; k < 64; ++k) a = fmaf(hb[k], lin2_w[k * 3 + j], a);
    lg[j] = a;
  }
  __syncthreads();
  if (j < 3) {
    float mx = fmaxf(fmaxf(lg[0], lg[1]), lg[2]);
    float lse = mx + logf(expf(lg[0] - mx) + expf(lg[1] - mx) + expf(lg[2] - mx));
    out[g * 3 + j] = lg[j] - lse;
  }
}

extern "C" void kernel_launch(void* const* d_in, const int* in_sizes, int n_in,
                              void* d_out, int out_size, void* d_ws, size_t ws_size,
                              hipStream_t stream) {
  const float* x        = (const float*)d_in[0];
  const int*   edge     = (const int*)d_in[1];
  const int*   batch    = (const int*)d_in[2];
  const float* eps      = (const float*)d_in[4];
  const float* W1_first = (const float*)d_in[5];
  const float* W1_rest  = (const float*)d_in[6];
  const float* b1       = (const float*)d_in[7];
  const float* g1       = (const float*)d_in[8];
  const float* be1      = (const float*)d_in[9];
  const float* m1       = (const float*)d_in[10];
  const float* v1       = (const float*)d_in[11];
  const float* W2       = (const float*)d_in[12];
  const float* b2       = (const float*)d_in[13];
  const float* g2       = (const float*)d_in[14];
  const float* be2      = (const float*)d_in[15];
  const float* m2       = (const float*)d_in[16];
  const float* v2       = (const float*)d_in[17];
  const float* lin1_w   = (const float*)d_in[18];
  const float* lin1_b   = (const float*)d_in[19];
  const float* lin2_w   = (const float*)d_in[20];
  const float* lin2_b   = (const float*)d_in[21];

  int N = in_sizes[0];
  int E = in_sizes[1] / 2;
  int G = out_size / 3;
  const int* esrc = edge;
  const int* edst = edge + E;
  int P = (N + (1 << ABITS) - 1) >> ABITS;  // dst-range buckets (N=100k -> 7)
  if (P > 32) P = 32;                        // LDS array bound (N < 512k)

  size_t off = 0;
  auto alloc = [&](size_t bytes) -> char* {
    char* p = (char*)d_ws + off;
    off += (bytes + 255) & ~(size_t)255;
    return p;
  };
  int SB = (N + 255) / 256;  // scan blocks (must be <= 1024)
  int*    deg    = (int*)alloc((size_t)N * 4);
  int*    rp     = (int*)alloc((size_t)(N + 1) * 4);
  int*    cursor = (int*)alloc((size_t)N * 4);
  int*    col    = (int*)alloc((size_t)E * 4);
  int*    bsum   = (int*)alloc((size_t)SB * 4);
  int*    boff   = (int*)alloc((size_t)SB * 4);
  int*    bc     = (int*)alloc((size_t)32 * 4);
  int*    asrc   = (int*)alloc((size_t)E * 4);
  int*    adst   = (int*)alloc((size_t)E * 4);
  int*    gs     = (int*)alloc((size_t)(G + 1) * 4);
  float*  w1t    = (float*)alloc((size_t)7 * 4096 * 4);
  float*  zbuf   = (float*)alloc((size_t)N * 64 * 4);
  ushort* hA     = (ushort*)alloc((size_t)N * 64 * 2);
  ushort* hB     = (ushort*)alloc((size_t)N * 64 * 2);
  float*  pooled = (float*)alloc((size_t)G * 512 * 4);
  (void)ws_size;

  hipMemsetAsync(deg, 0, (size_t)N * 4, stream);
  int eb = (E + 255) / 256;
  count_deg_kernel<<<eb, 256, 0, stream>>>(edst, deg, E);
  scan_blocksums<<<SB, 256, 0, stream>>>(deg, bsum, N);
  scan_bsum<<<1, 1024, 0, stream>>>(bsum, boff, rp + N, SB);
  scan_final<<<SB, 256, 0, stream>>>(deg, boff, rp, cursor, N);

  // two-phase binned CSC build
  init_buckets_kernel<<<1, 64, 0, stream>>>(rp, bc, N, P);
  int ebA = (E + 4095) / 4096;
  bin_edges_kernel<<<ebA, 1024, 0, stream>>>(esrc, edst, bc, asrc, adst, E);
  for (int b = 0; b < P; ++b) {
    int lo = b << ABITS;
    int hi = (b + 1) << ABITS;
    if (hi > N) hi = N;
    if (lo >= N) break;
    scatter_bucket_kernel<<<1024, 256, 0, stream>>>(asrc, adst, rp, cursor, col, lo, hi);
  }

  graph_bounds_kernel<<<SB, 256, 0, stream>>>(batch, gs, N, G);
  transpose_w1_kernel<<<7, 256, 0, stream>>>(W1_rest, w1t);

  int nb64 = (N + 63) / 64;
  layer0_kernel<<<nb64, 64, 0, stream>>>(x, rp, col, eps, W1_first,
      b1, g1, be1, m1, v1, W2, b2, g2, be2, m2, v2, hA, N);
  pool_kernel<<<G, 256, 0, stream>>>(hA, gs, pooled, 0, G);

  ushort* hin = hA;
  ushort* hout = hB;
  for (int i = 1; i < 8; ++i) {
    agg_kernel<<<2048, 256, 0, stream>>>(hin, rp, col, eps, i, zbuf, N);
    mlp_kernel<<<nb64, 64, 0, stream>>>(zbuf, hout,
        w1t + (size_t)(i - 1) * 4096,
        b1 + i * 64, g1 + i * 64, be1 + i * 64, m1 + i * 64, v1 + i * 64,
        W2 + (size_t)i * 4096,
        b2 + i * 64, g2 + i * 64, be2 + i * 64, m2 + i * 64, v2 + i * 64, N);
    pool_kernel<<<G, 256, 0, stream>>>(hout, gs, pooled, i, G);
    ushort* t = hin; hin = hout; hout = t;
  }
  final_kernel<<<G, 64, 0, stream>>>(pooled, gs, lin1_w, lin1_b,
                                     lin2_w, lin2_b, (float*)d_out, G);
}

// Round 7
// 1287.434 us; speedup vs baseline: 1.0051x; 1.0051x over previous
//
#include <hip/hip_runtime.h>
#include <hip/hip_bf16.h>
#include <math.h>

// ---------------------------------------------------------------------------
// GIN + JumpingKnowledge(cat) + mean-pool + 2-layer head, eval mode.
// R7: mlp/layer0 __launch_bounds__(64,1) — R6 profile showed VGPR_Count=72
//     for a kernel needing 128+ live floats (zv[64]+out2[64]): the default
//     occupancy cap forced scratch spills, 77us vs ~10us VALU roofline.
//     (64,1) releases the full VGPR budget; arrays registerize.
// Everything else unchanged from R6 (binned CSC build, bf16 h table, R5 agg).
// ---------------------------------------------------------------------------

typedef unsigned int uint;
typedef unsigned short ushort;

#define ABITS 14  // bucket = dst >> 14 (16384 nodes/bucket, ~1MB col window)

__device__ __forceinline__ float bf_lo(uint w) { return __uint_as_float(w << 16); }
__device__ __forceinline__ float bf_hi(uint w) { return __uint_as_float(w & 0xffff0000u); }

__device__ __forceinline__ uint pack_bf16(float a, float b) {
  __hip_bfloat16 ha = __float2bfloat16(a);
  __hip_bfloat16 hb = __float2bfloat16(b);
  ushort ua = *(ushort*)&ha, ub = *(ushort*)&hb;
  return (uint)ua | ((uint)ub << 16);
}

__global__ void count_deg_kernel(const int* __restrict__ dst, int* __restrict__ deg, int E) {
  int t = blockIdx.x * blockDim.x + threadIdx.x;
  if (t < E) atomicAdd(&deg[dst[t]], 1);
}

// ---- multi-block exclusive scan: deg[N] -> rp[N+1] (+ cursor copy) --------
__global__ void scan_blocksums(const int* __restrict__ deg, int* __restrict__ bsum, int N) {
  __shared__ int red[256];
  int i = blockIdx.x * 256 + threadIdx.x;
  red[threadIdx.x] = (i < N) ? deg[i] : 0;
  __syncthreads();
  for (int off = 128; off > 0; off >>= 1) {
    if (threadIdx.x < off) red[threadIdx.x] += red[threadIdx.x + off];
    __syncthreads();
  }
  if (threadIdx.x == 0) bsum[blockIdx.x] = red[0];
}

__global__ void scan_bsum(const int* __restrict__ bsum, int* __restrict__ boff,
                          int* __restrict__ rp_last, int B) {
  __shared__ int tmp[1024];
  int t = threadIdx.x;
  int v = (t < B) ? bsum[t] : 0;
  tmp[t] = v;
  __syncthreads();
  for (int off = 1; off < 1024; off <<= 1) {
    int u = (t >= off) ? tmp[t - off] : 0;
    __syncthreads();
    tmp[t] += u;
    __syncthreads();
  }
  if (t < B) boff[t] = tmp[t] - v;
  if (t == 1023) *rp_last = tmp[1023];
}

__global__ void scan_final(const int* __restrict__ deg, const int* __restrict__ boff,
                           int* __restrict__ rp, int* __restrict__ cursor, int N) {
  __shared__ int tmp[256];
  int i = blockIdx.x * 256 + threadIdx.x;
  int v = (i < N) ? deg[i] : 0;
  tmp[threadIdx.x] = v;
  __syncthreads();
  for (int off = 1; off < 256; off <<= 1) {
    int u = (threadIdx.x >= off) ? tmp[threadIdx.x - off] : 0;
    __syncthreads();
    tmp[threadIdx.x] += u;
    __syncthreads();
  }
  if (i < N) {
    int ex = boff[blockIdx.x] + tmp[threadIdx.x] - v;
    rp[i] = ex;
    cursor[i] = ex;
  }
}

// bucket arena cursors: bc[b] = rp[b<<ABITS] (arena ranges == col ranges)
__global__ void init_buckets_kernel(const int* __restrict__ rp, int* __restrict__ bc,
                                    int N, int P) {
  int b = threadIdx.x;
  if (b < P) {
    int lo = b << ABITS;
    if (lo > N) lo = N;
    bc[b] = rp[lo];
  }
}

// Phase A: partition edges into dst-range buckets. 1024 thr x 4 edges/block.
__global__ __launch_bounds__(1024) void bin_edges_kernel(
    const int* __restrict__ src, const int* __restrict__ dst, int* __restrict__ bc,
    int* __restrict__ arena_src, int* __restrict__ arena_dst, int E) {
  __shared__ int cnt[32], base[32];
  for (long chunk = (long)blockIdx.x * 4096; chunk < E; chunk += (long)gridDim.x * 4096) {
    if (threadIdx.x < 32) cnt[threadIdx.x] = 0;
    __syncthreads();
    int s[4], d[4], b[4], r[4];
#pragma unroll
    for (int u = 0; u < 4; ++u) {
      long e = chunk + threadIdx.x + u * 1024;
      if (e < E) {
        s[u] = src[e];
        d[u] = dst[e];
        b[u] = d[u] >> ABITS;
        r[u] = atomicAdd(&cnt[b[u]], 1);
      }
    }
    __syncthreads();
    if (threadIdx.x < 32) base[threadIdx.x] = cnt[threadIdx.x] ? atomicAdd(&bc[threadIdx.x], cnt[threadIdx.x]) : 0;
    __syncthreads();
#pragma unroll
    for (int u = 0; u < 4; ++u) {
      long e = chunk + threadIdx.x + u * 1024;
      if (e < E) {
        int pos = base[b[u]] + r[u];
        arena_src[pos] = s[u];
        arena_dst[pos] = d[u];
      }
    }
    __syncthreads();
  }
}

// Phase B: scatter one bucket; col writes confined to a ~1MB L2-resident window.
__global__ void scatter_bucket_kernel(const int* __restrict__ arena_src,
                                      const int* __restrict__ arena_dst,
                                      const int* __restrict__ rp, int* __restrict__ cursor,
                                      int* __restrict__ col, int lo_node, int hi_node) {
  int start = rp[lo_node], end = rp[hi_node];
  for (int i = start + (int)(blockIdx.x * blockDim.x + threadIdx.x); i < end;
       i += (int)(gridDim.x * blockDim.x)) {
    int s = arena_src[i], d = arena_dst[i];
    int pos = atomicAdd(&cursor[d], 1);
    col[pos] = s;
  }
}

// graph start offsets from sorted batch: gs[g] = first node of graph g, gs[G]=N.
__global__ void graph_bounds_kernel(const int* __restrict__ batch, int* __restrict__ gs,
                                    int N, int G) {
  int n = blockIdx.x * 256 + threadIdx.x;
  if (n >= N) return;
  int b = batch[n];
  int bp = (n == 0) ? -1 : batch[n - 1];
  for (int g = bp + 1; g <= b; ++g) gs[g] = n;
  if (n == N - 1)
    for (int g = b + 1; g <= G; ++g) gs[g] = N;
}

// W1_rest [7][64][64] -> W1T [7][64][64] with W1T[l][k][m] = W1_rest[l][m][k]
__global__ void transpose_w1_kernel(const float* __restrict__ w1rest, float* __restrict__ w1t) {
  int l = blockIdx.x;
  for (int idx = threadIdx.x; idx < 4096; idx += blockDim.x) {
    int k = idx >> 6, m = idx & 63;
    w1t[l * 4096 + idx] = w1rest[l * 4096 + m * 64 + k];
  }
}

// z[n][:] = (1+eps_l)*h[n][:] + sum_e h[col[e]][:]   (h bf16, z fp32)
// 8-lane groups; 4 independent 1KB row-gathers in flight (2 nodes x 2 steps).
__global__ __launch_bounds__(256, 6) void agg_kernel(
    const ushort* __restrict__ hb, const int* __restrict__ rp,
    const int* __restrict__ col, const float* __restrict__ eps,
    int layer, float* __restrict__ z, int N) {
  int lane = threadIdx.x & 63;
  int g = lane >> 3;
  int r = lane & 7;
  int wave = blockIdx.x * (blockDim.x >> 6) + (threadIdx.x >> 6);
  int nwaves = gridDim.x * (blockDim.x >> 6);
  float ep = 1.0f + eps[layer];
  for (int n = wave * 2; n < N; n += nwaves * 2) {
    int n0 = __builtin_amdgcn_readfirstlane(n);
    int n1 = n0 + 1;
    int beg0 = rp[n0];
    int end0 = rp[n0 + 1];
    int end1 = (n1 < N) ? rp[n1 + 1] : end0;
    float a0[8] = {0.f, 0.f, 0.f, 0.f, 0.f, 0.f, 0.f, 0.f};
    float a1[8] = {0.f, 0.f, 0.f, 0.f, 0.f, 0.f, 0.f, 0.f};
    float b0[8] = {0.f, 0.f, 0.f, 0.f, 0.f, 0.f, 0.f, 0.f};
    float b1[8] = {0.f, 0.f, 0.f, 0.f, 0.f, 0.f, 0.f, 0.f};
    int e0 = beg0 + g;
    int e1 = end0 + g;
    while (e0 < end0 || e1 < end1) {
      if (e0 < end0) {
        int s = col[e0];
        uint4 w = ((const uint4*)(hb + (long)s * 64))[r];
        a0[0] += bf_lo(w.x); a0[1] += bf_hi(w.x);
        a0[2] += bf_lo(w.y); a0[3] += bf_hi(w.y);
        a0[4] += bf_lo(w.z); a0[5] += bf_hi(w.z);
        a0[6] += bf_lo(w.w); a0[7] += bf_hi(w.w);
      }
      if (e0 + 8 < end0) {
        int s = col[e0 + 8];
        uint4 w = ((const uint4*)(hb + (long)s * 64))[r];
        a1[0] += bf_lo(w.x); a1[1] += bf_hi(w.x);
        a1[2] += bf_lo(w.y); a1[3] += bf_hi(w.y);
        a1[4] += bf_lo(w.z); a1[5] += bf_hi(w.z);
        a1[6] += bf_lo(w.w); a1[7] += bf_hi(w.w);
      }
      if (e1 < end1) {
        int s = col[e1];
        uint4 w = ((const uint4*)(hb + (long)s * 64))[r];
        b0[0] += bf_lo(w.x); b0[1] += bf_hi(w.x);
        b0[2] += bf_lo(w.y); b0[3] += bf_hi(w.y);
        b0[4] += bf_lo(w.z); b0[5] += bf_hi(w.z);
        b0[6] += bf_lo(w.w); b0[7] += bf_hi(w.w);
      }
      if (e1 + 8 < end1) {
        int s = col[e1 + 8];
        uint4 w = ((const uint4*)(hb + (long)s * 64))[r];
        b1[0] += bf_lo(w.x); b1[1] += bf_hi(w.x);
        b1[2] += bf_lo(w.y); b1[3] += bf_hi(w.y);
        b1[4] += bf_lo(w.z); b1[5] += bf_hi(w.z);
        b1[6] += bf_lo(w.w); b1[7] += bf_hi(w.w);
      }
      e0 += 16; e1 += 16;
    }
#pragma unroll
    for (int j = 0; j < 8; ++j) { a0[j] += a1[j]; b0[j] += b1[j]; }
#pragma unroll
    for (int m = 8; m <= 32; m <<= 1) {
#pragma unroll
      for (int j = 0; j < 8; ++j) {
        a0[j] += __shfl_xor(a0[j], m, 64);
        b0[j] += __shfl_xor(b0[j], m, 64);
      }
    }
    if (g == 0) {
      uint4 hv = ((const uint4*)(hb + (long)n0 * 64))[r];
      float4 z0, z1;
      z0.x = fmaf(ep, bf_lo(hv.x), a0[0]); z0.y = fmaf(ep, bf_hi(hv.x), a0[1]);
      z0.z = fmaf(ep, bf_lo(hv.y), a0[2]); z0.w = fmaf(ep, bf_hi(hv.y), a0[3]);
      z1.x = fmaf(ep, bf_lo(hv.z), a0[4]); z1.y = fmaf(ep, bf_hi(hv.z), a0[5]);
      z1.z = fmaf(ep, bf_lo(hv.w), a0[6]); z1.w = fmaf(ep, bf_hi(hv.w), a0[7]);
      float4* zr = (float4*)(z + (long)n0 * 64 + r * 8);
      zr[0] = z0; zr[1] = z1;
    } else if (g == 1 && n1 < N) {
      uint4 hv = ((const uint4*)(hb + (long)n1 * 64))[r];
      float4 z0, z1;
      z0.x = fmaf(ep, bf_lo(hv.x), b0[0]); z0.y = fmaf(ep, bf_hi(hv.x), b0[1]);
      z0.z = fmaf(ep, bf_lo(hv.y), b0[2]); z0.w = fmaf(ep, bf_hi(hv.y), b0[3]);
      z1.x = fmaf(ep, bf_lo(hv.z), b0[4]); z1.y = fmaf(ep, bf_hi(hv.z), b0[5]);
      z1.z = fmaf(ep, bf_lo(hv.w), b0[6]); z1.w = fmaf(ep, bf_hi(hv.w), b0[7]);
      float4* zr = (float4*)(z + (long)n1 * 64 + r * 8);
      zr[0] = z0; zr[1] = z1;
    }
  }
}

// Fused 64->64->64 MLP + relu/bn twice. One node per lane; z fp32 in, h bf16 out.
// (64,1): full VGPR budget -> zv/out2 fully registerized (R6: VGPR=72 = spills).
__global__ __launch_bounds__(64, 1) void mlp_kernel(
    const float* __restrict__ z, ushort* __restrict__ hout,
    const float* __restrict__ W1T, const float* __restrict__ b1,
    const float* __restrict__ g1, const float* __restrict__ be1,
    const float* __restrict__ m1, const float* __restrict__ v1,
    const float* __restrict__ W2, const float* __restrict__ b2,
    const float* __restrict__ g2, const float* __restrict__ be2,
    const float* __restrict__ m2, const float* __restrict__ v2, int N) {
  int n = blockIdx.x * blockDim.x + threadIdx.x;
  if (n >= N) return;
  float zv[64];
  const float4* zp = (const float4*)(z + (long)n * 64);
#pragma unroll
  for (int q = 0; q < 16; ++q) {
    float4 t = zp[q];
    zv[4 * q + 0] = t.x; zv[4 * q + 1] = t.y; zv[4 * q + 2] = t.z; zv[4 * q + 3] = t.w;
  }
  float out2[64];
#pragma unroll
  for (int j = 0; j < 64; ++j) out2[j] = b2[j];
  for (int k = 0; k < 64; ++k) {
    const float* w1c = W1T + k * 64;
    float t0 = b1[k], t1 = 0.f, t2 = 0.f, t3 = 0.f;
#pragma unroll
    for (int m = 0; m < 16; ++m) {
      t0 = fmaf(zv[4 * m + 0], w1c[4 * m + 0], t0);
      t1 = fmaf(zv[4 * m + 1], w1c[4 * m + 1], t1);
      t2 = fmaf(zv[4 * m + 2], w1c[4 * m + 2], t2);
      t3 = fmaf(zv[4 * m + 3], w1c[4 * m + 3], t3);
    }
    float t = (t0 + t1) + (t2 + t3);
    t = fmaxf(t, 0.f);
    float sc = g1[k] * rsqrtf(v1[k] + 1e-5f);
    t = fmaf(t - m1[k], sc, be1[k]);
    const float* w2r = W2 + k * 64;
#pragma unroll
    for (int j = 0; j < 64; ++j) out2[j] = fmaf(t, w2r[j], out2[j]);
  }
  uint4* hp = (uint4*)(hout + (long)n * 64);
#pragma unroll
  for (int q = 0; q < 8; ++q) {
    float u[8];
#pragma unroll
    for (int c = 0; c < 8; ++c) {
      int j = 8 * q + c;
      float t = fmaxf(out2[j], 0.f);
      u[c] = fmaf(t - m2[j], g2[j] * rsqrtf(v2[j] + 1e-5f), be2[j]);
    }
    uint4 w;
    w.x = pack_bf16(u[0], u[1]);
    w.y = pack_bf16(u[2], u[3]);
    w.z = pack_bf16(u[4], u[5]);
    w.w = pack_bf16(u[6], u[7]);
    hp[q] = w;
  }
}

// Layer 0: scalar input (H_in = 1).  Thread-per-node, fully fused, bf16 out.
__global__ __launch_bounds__(64, 1) void layer0_kernel(
    const float* __restrict__ x, const int* __restrict__ rp, const int* __restrict__ col,
    const float* __restrict__ eps,
    const float* __restrict__ W1f, const float* __restrict__ b1,
    const float* __restrict__ g1, const float* __restrict__ be1,
    const float* __restrict__ m1, const float* __restrict__ v1,
    const float* __restrict__ W2, const float* __restrict__ b2,
    const float* __restrict__ g2, const float* __restrict__ be2,
    const float* __restrict__ m2, const float* __restrict__ v2,
    ushort* __restrict__ hout, int N) {
  int n = blockIdx.x * blockDim.x + threadIdx.x;
  if (n >= N) return;
  int beg = rp[n], end = rp[n + 1];
  float agg = 0.f;
  for (int e = beg; e < end; ++e) agg += x[col[e]];
  float z0 = fmaf(1.0f + eps[0], x[n], agg);
  float out2[64];
#pragma unroll
  for (int j = 0; j < 64; ++j) out2[j] = b2[j];
  for (int k = 0; k < 64; ++k) {
    float t = fmaf(z0, W1f[k], b1[k]);
    t = fmaxf(t, 0.f);
    float sc = g1[k] * rsqrtf(v1[k] + 1e-5f);
    t = fmaf(t - m1[k], sc, be1[k]);
    const float* w2r = W2 + k * 64;
#pragma unroll
    for (int j = 0; j < 64; ++j) out2[j] = fmaf(t, w2r[j], out2[j]);
  }
  uint4* hp = (uint4*)(hout + (long)n * 64);
#pragma unroll
  for (int q = 0; q < 8; ++q) {
    float u[8];
#pragma unroll
    for (int c = 0; c < 8; ++c) {
      int j = 8 * q + c;
      float t = fmaxf(out2[j], 0.f);
      u[c] = fmaf(t - m2[j], g2[j] * rsqrtf(v2[j] + 1e-5f), be2[j]);
    }
    uint4 w;
    w.x = pack_bf16(u[0], u[1]);
    w.y = pack_bf16(u[2], u[3]);
    w.z = pack_bf16(u[4], u[5]);
    w.w = pack_bf16(u[6], u[7]);
    hp[q] = w;
  }
}

// block-per-graph mean-sum using precomputed bounds; no atomics.
__global__ void pool_kernel(const ushort* __restrict__ hb, const int* __restrict__ gs,
                            float* __restrict__ pooled, int layer, int G) {
  int g = blockIdx.x;
  int s = gs[g], e = gs[g + 1];
  int w = threadIdx.x >> 6, lane = threadIdx.x & 63;
  float acc = 0.f;
  for (int n = s + w; n < e; n += 4) {
    ushort u = hb[(long)n * 64 + lane];
    acc += __uint_as_float((uint)u << 16);
  }
  __shared__ float red[4][64];
  red[w][lane] = acc;
  __syncthreads();
  if (w == 0)
    pooled[(long)g * 512 + layer * 64 + lane] =
        ((red[0][lane] + red[1][lane]) + (red[2][lane] + red[3][lane]));
}

__global__ __launch_bounds__(64) void final_kernel(
    const float* __restrict__ pooled, const int* __restrict__ gs,
    const float* __restrict__ lin1_w, const float* __restrict__ lin1_b,
    const float* __restrict__ lin2_w, const float* __restrict__ lin2_b,
    float* __restrict__ out, int G) {
  int g = blockIdx.x;
  int j = threadIdx.x;
  float inv = 1.0f / fmaxf((float)(gs[g + 1] - gs[g]), 1.0f);
  __shared__ float p[512];
  for (int t = j; t < 512; t += 64) p[t] = pooled[(long)g * 512 + t] * inv;
  __syncthreads();
  float a0 = lin1_b[j], a1 = 0.f, a2 = 0.f, a3 = 0.f;
  for (int k = 0; k < 512; k += 4) {
    a0 = fmaf(p[k + 0], lin1_w[(k + 0) * 64 + j], a0);
    a1 = fmaf(p[k + 1], lin1_w[(k + 1) * 64 + j], a1);
    a2 = fmaf(p[k + 2], lin1_w[(k + 2) * 64 + j], a2);
    a3 = fmaf(p[k + 3], lin1_w[(k + 3) * 64 + j], a3);
  }
  float hv = fmaxf((a0 + a1) + (a2 + a3), 0.f);
  __shared__ float hb[64];
  hb[j] = hv;
  __syncthreads();
  __shared__ float lg[3];
  if (j < 3) {
    float a = lin2_b[j];
#pragma unroll
    for (int k = 0; k < 64; ++k) a = fmaf(hb[k], lin2_w[k * 3 + j], a);
    lg[j] = a;
  }
  __syncthreads();
  if (j < 3) {
    float mx = fmaxf(fmaxf(lg[0], lg[1]), lg[2]);
    float lse = mx + logf(expf(lg[0] - mx) + expf(lg[1] - mx) + expf(lg[2] - mx));
    out[g * 3 + j] = lg[j] - lse;
  }
}

extern "C" void kernel_launch(void* const* d_in, const int* in_sizes, int n_in,
                              void* d_out, int out_size, void* d_ws, size_t ws_size,
                              hipStream_t stream) {
  const float* x        = (const float*)d_in[0];
  const int*   edge     = (const int*)d_in[1];
  const int*   batch    = (const int*)d_in[2];
  const float* eps      = (const float*)d_in[4];
  const float* W1_first = (const float*)d_in[5];
  const float* W1_rest  = (const float*)d_in[6];
  const float* b1       = (const float*)d_in[7];
  const float* g1       = (const float*)d_in[8];
  const float* be1      = (const float*)d_in[9];
  const float* m1       = (const float*)d_in[10];
  const float* v1       = (const float*)d_in[11];
  const float* W2       = (const float*)d_in[12];
  const float* b2       = (const float*)d_in[13];
  const float* g2       = (const float*)d_in[14];
  const float* be2      = (const float*)d_in[15];
  const float* m2       = (const float*)d_in[16];
  const float* v2       = (const float*)d_in[17];
  const float* lin1_w   = (const float*)d_in[18];
  const float* lin1_b   = (const float*)d_in[19];
  const float* lin2_w   = (const float*)d_in[20];
  const float* lin2_b   = (const float*)d_in[21];

  int N = in_sizes[0];
  int E = in_sizes[1] / 2;
  int G = out_size / 3;
  const int* esrc = edge;
  const int* edst = edge + E;
  int P = (N + (1 << ABITS) - 1) >> ABITS;  // dst-range buckets (N=100k -> 7)
  if (P > 32) P = 32;                        // LDS array bound (N < 512k)

  size_t off = 0;
  auto alloc = [&](size_t bytes) -> char* {
    char* p = (char*)d_ws + off;
    off += (bytes + 255) & ~(size_t)255;
    return p;
  };
  int SB = (N + 255) / 256;  // scan blocks (must be <= 1024)
  int*    deg    = (int*)alloc((size_t)N * 4);
  int*    rp     = (int*)alloc((size_t)(N + 1) * 4);
  int*    cursor = (int*)alloc((size_t)N * 4);
  int*    col    = (int*)alloc((size_t)E * 4);
  int*    bsum   = (int*)alloc((size_t)SB * 4);
  int*    boff   = (int*)alloc((size_t)SB * 4);
  int*    bc     = (int*)alloc((size_t)32 * 4);
  int*    asrc   = (int*)alloc((size_t)E * 4);
  int*    adst   = (int*)alloc((size_t)E * 4);
  int*    gs     = (int*)alloc((size_t)(G + 1) * 4);
  float*  w1t    = (float*)alloc((size_t)7 * 4096 * 4);
  float*  zbuf   = (float*)alloc((size_t)N * 64 * 4);
  ushort* hA     = (ushort*)alloc((size_t)N * 64 * 2);
  ushort* hB     = (ushort*)alloc((size_t)N * 64 * 2);
  float*  pooled = (float*)alloc((size_t)G * 512 * 4);
  (void)ws_size;

  hipMemsetAsync(deg, 0, (size_t)N * 4, stream);
  int eb = (E + 255) / 256;
  count_deg_kernel<<<eb, 256, 0, stream>>>(edst, deg, E);
  scan_blocksums<<<SB, 256, 0, stream>>>(deg, bsum, N);
  scan_bsum<<<1, 1024, 0, stream>>>(bsum, boff, rp + N, SB);
  scan_final<<<SB, 256, 0, stream>>>(deg, boff, rp, cursor, N);

  // two-phase binned CSC build
  init_buckets_kernel<<<1, 64, 0, stream>>>(rp, bc, N, P);
  int ebA = (E + 4095) / 4096;
  bin_edges_kernel<<<ebA, 1024, 0, stream>>>(esrc, edst, bc, asrc, adst, E);
  for (int b = 0; b < P; ++b) {
    int lo = b << ABITS;
    int hi = (b + 1) << ABITS;
    if (hi > N) hi = N;
    if (lo >= N) break;
    scatter_bucket_kernel<<<1024, 256, 0, stream>>>(asrc, adst, rp, cursor, col, lo, hi);
  }

  graph_bounds_kernel<<<SB, 256, 0, stream>>>(batch, gs, N, G);
  transpose_w1_kernel<<<7, 256, 0, stream>>>(W1_rest, w1t);

  int nb64 = (N + 63) / 64;
  layer0_kernel<<<nb64, 64, 0, stream>>>(x, rp, col, eps, W1_first,
      b1, g1, be1, m1, v1, W2, b2, g2, be2, m2, v2, hA, N);
  pool_kernel<<<G, 256, 0, stream>>>(hA, gs, pooled, 0, G);

  ushort* hin = hA;
  ushort* hout = hB;
  for (int i = 1; i < 8; ++i) {
    agg_kernel<<<2048, 256, 0, stream>>>(hin, rp, col, eps, i, zbuf, N);
    mlp_kernel<<<nb64, 64, 0, stream>>>(zbuf, hout,
        w1t + (size_t)(i - 1) * 4096,
        b1 + i * 64, g1 + i * 64, be1 + i * 64, m1 + i * 64, v1 + i * 64,
        W2 + (size_t)i * 4096,
        b2 + i * 64, g2 + i * 64, be2 + i * 64, m2 + i * 64, v2 + i * 64, N);
    pool_kernel<<<G, 256, 0, stream>>>(hout, gs, pooled, i, G);
    ushort* t = hin; hin = hout; hout = t;
  }
  final_kernel<<<G, 64, 0, stream>>>(pooled, gs, lin1_w, lin1_b,
                                     lin2_w, lin2_b, (float*)d_out, G);
}